// Round 1
// baseline (5030.046 us; speedup 1.0000x reference)
//
#include <hip/hip_runtime.h>
#include <cstdint>

#define B_  8
#define HH  256
#define WW  256
#define HP  258
#define WP  258
#define PIX (HH*WW)

using bf16x8  = __attribute__((ext_vector_type(8))) short;
using floatx4 = __attribute__((ext_vector_type(4))) float;

__device__ __forceinline__ unsigned short f2bf(float f) {
  union { float f; unsigned u; } v; v.f = f;
  unsigned r = v.u + 0x7FFFu + ((v.u >> 16) & 1u);   // RNE
  return (unsigned short)(r >> 16);
}

__device__ __forceinline__ void gl_lds16(const void* g, void* l) {
  __builtin_amdgcn_global_load_lds(
      (const __attribute__((address_space(1))) void*)g,
      (__attribute__((address_space(3))) void*)l, 16, 0, 0);
}

// ---------- weight prep ----------
// w1r[t][ck][n][kk] = bf16(Wg1[n][ck*32+kk][kh][kw]), t = kh*3+kw
__global__ __launch_bounds__(256) void k_prep_w1(const float* __restrict__ Wg1,
                                                 unsigned short* __restrict__ w1r) {
  int i = blockIdx.x * 256 + threadIdx.x;
  if (i >= 9 * 8 * 128 * 32) return;
  int kk = i & 31, n = (i >> 5) & 127, ck = (i >> 12) & 7, t = i >> 15;
  int c = ck * 32 + kk, kh = t / 3, kw = t - kh * 3;
  w1r[i] = f2bf(Wg1[((n * 256 + c) * 3 + kh) * 3 + kw]);
}

// w2r[t][ck][n(16)][kk] ; n>=9 zero-padded
__global__ __launch_bounds__(256) void k_prep_w2(const float* __restrict__ Wg2,
                                                 unsigned short* __restrict__ w2r) {
  int i = blockIdx.x * 256 + threadIdx.x;
  if (i >= 9 * 4 * 16 * 32) return;
  int kk = i & 31, n = (i >> 5) & 15, ck = (i >> 9) & 3, t = i >> 11;
  int c = ck * 32 + kk, kh = t / 3, kw = t - kh * 3;
  float v = (n < 9) ? Wg2[((n * 128 + c) * 3 + kh) * 3 + kw] : 0.f;
  w2r[i] = f2bf(v);
}

// WxT/WyT transposed fp32 (for scalar-load-friendly embed), BN scale/shift
__global__ __launch_bounds__(256) void k_prep_misc(
    const float* __restrict__ Wx, const float* __restrict__ Wy,
    const float* __restrict__ gamma, const float* __restrict__ beta,
    const float* __restrict__ mean, const float* __restrict__ var,
    float* __restrict__ WxT, float* __restrict__ WyT, float* __restrict__ bnss) {
  int i = blockIdx.x * 256 + threadIdx.x;
  if (i < 4096) { WxT[i] = Wx[(i & 63) * 64 + (i >> 6)]; return; }
  if (i < 8192) { int j = i - 4096; WyT[j] = Wy[(j & 63) * 64 + (j >> 6)]; return; }
  if (i < 8320) {
    int n = i - 8192;
    float sc = gamma[n] * rsqrtf(var[n] + 1e-5f);
    bnss[n] = sc; bnss[128 + n] = beta[n] - mean[n] * sc;
  }
}

// zero 1-px borders of padded gi (256ch) and h (128ch); uint = 2 bf16
__global__ __launch_bounds__(256) void k_zero_border(unsigned int* __restrict__ gi32,
                                                     unsigned int* __restrict__ h32) {
  int i = blockIdx.x * 256 + threadIdx.x;
  if (i >= 8 * 1028 * 192) return;
  int slot = i % 192;
  int pidx = i / 192;
  int b = pidx / 1028;
  int p = pidx - b * 1028;
  int hp, wp;
  if (p < 258)      { hp = 0;           wp = p; }
  else if (p < 516) { hp = 257;         wp = p - 258; }
  else if (p < 772) { hp = p - 516 + 1; wp = 0; }
  else              { hp = p - 772 + 1; wp = 257; }
  size_t pix = ((size_t)b * HP + hp) * WP + wp;
  if (slot < 128) gi32[pix * 128 + slot] = 0u;
  else            h32[pix * 64 + (slot - 128)] = 0u;
}

// ---------- embeddings: 1x1 convs, l2norm, r0, gi = [xn|yn||xn-yn||xn*yn] ----------
__global__ __launch_bounds__(256) void k_embed(
    const float* __restrict__ x, const float* __restrict__ y,
    const float* __restrict__ WxT, const float* __restrict__ WyT,
    unsigned int* __restrict__ gi32, float* __restrict__ r0) {
  int blk = blockIdx.x;            // b*256 + h
  int b = blk >> 8, h = blk & 255, w = threadIdx.x;
  size_t base = ((size_t)b * 64) * PIX + h * 256 + w;

  float xe[64];
#pragma unroll
  for (int e = 0; e < 64; ++e) xe[e] = 0.f;
#pragma unroll
  for (int c = 0; c < 64; ++c) {
    float xc = x[base + (size_t)c * PIX];
    const float* wr = WxT + c * 64;
#pragma unroll
    for (int e = 0; e < 64; ++e) xe[e] = fmaf(wr[e], xc, xe[e]);
  }
  float ye[64];
#pragma unroll
  for (int e = 0; e < 64; ++e) ye[e] = 0.f;
#pragma unroll
  for (int c = 0; c < 64; ++c) {
    float yc = y[base + (size_t)c * PIX];
    const float* wr = WyT + c * 64;
#pragma unroll
    for (int e = 0; e < 64; ++e) ye[e] = fmaf(wr[e], yc, ye[e]);
  }
  float sx = 0.f, sy = 0.f, sxy = 0.f;
#pragma unroll
  for (int e = 0; e < 64; ++e) {
    sx = fmaf(xe[e], xe[e], sx);
    sy = fmaf(ye[e], ye[e], sy);
    sxy = fmaf(xe[e], ye[e], sxy);
  }
  float inx = 1.f / (sqrtf(sx) + 1e-6f);
  float iny = 1.f / (sqrtf(sy) + 1e-6f);
  r0[b * PIX + h * 256 + w] = (sxy * inx * iny + 1.f) * 0.5f;

  size_t gbase = (((size_t)b * HP + (h + 1)) * WP + (w + 1)) * 128;  // uint idx
#pragma unroll
  for (int e = 0; e < 64; e += 2) {
    float a0 = xe[e] * inx, a1 = xe[e + 1] * inx;
    float b0 = ye[e] * iny, b1 = ye[e + 1] * iny;
    gi32[gbase +      (e >> 1)] = (unsigned)f2bf(a0) | ((unsigned)f2bf(a1) << 16);
    gi32[gbase + 32 + (e >> 1)] = (unsigned)f2bf(b0) | ((unsigned)f2bf(b1) << 16);
    gi32[gbase + 64 + (e >> 1)] = (unsigned)f2bf(fabsf(a0 - b0)) | ((unsigned)f2bf(fabsf(a1 - b1)) << 16);
    gi32[gbase + 96 + (e >> 1)] = (unsigned)f2bf(a0 * b0) | ((unsigned)f2bf(a1 * b1) << 16);
  }
}

// ---------- conv1: 3x3 256->128 implicit-GEMM + BN + ReLU ----------
// BM=128 (pixels along W), BN=128, BK=32, 9 taps * 8 chunks = 72 K-iters
__global__ __launch_bounds__(256) void k_conv1(
    const unsigned short* __restrict__ gi,   // [B][HP][WP][256] bf16
    const unsigned short* __restrict__ w1r,  // [9][8][128][32]  bf16
    const float* __restrict__ bnss,
    unsigned short* __restrict__ hb) {       // [B][HP][WP][128] bf16
  __shared__ __align__(16) unsigned short As[128 * 32];
  __shared__ __align__(16) unsigned short Bs[128 * 32];
  int tid = threadIdx.x;
  int blk = blockIdx.x;                      // b*512 + h*2 + wt
  int wt = blk & 1, h = (blk >> 1) & 255, b = blk >> 9;
  int w0 = wt << 7;
  int wave = tid >> 6, lane = tid & 63;
  int wr = (wave >> 1) * 64, wc = (wave & 1) * 64;
  int quad = lane >> 4, l16 = lane & 15;

  const floatx4 z4 = {0.f, 0.f, 0.f, 0.f};
  floatx4 acc[4][4];
#pragma unroll
  for (int i = 0; i < 4; ++i)
#pragma unroll
    for (int j = 0; j < 4; ++j) acc[i][j] = z4;

  for (int t = 0; t < 9; ++t) {
    int dy = t / 3 - 1, dx = t % 3 - 1;
    const unsigned short* arow =
        gi + (((size_t)b * HP + (h + 1 + dy)) * WP + (w0 + 1 + dx)) * 256;
    for (int ck = 0; ck < 8; ++ck) {
      const char* asrc = (const char*)(arow + ck * 32);
      const char* bsrc = (const char*)(w1r + (((size_t)t * 8 + ck) << 12));
      int s0 = tid, s1 = tid + 256;
      gl_lds16(asrc + (s0 >> 2) * 512 + (s0 & 3) * 16, (char*)As + s0 * 16);
      gl_lds16(asrc + (s1 >> 2) * 512 + (s1 & 3) * 16, (char*)As + s1 * 16);
      gl_lds16(bsrc + tid * 16,        (char*)Bs + tid * 16);
      gl_lds16(bsrc + tid * 16 + 4096, (char*)Bs + tid * 16 + 4096);
      __syncthreads();
      bf16x8 af[4], bfr[4];
#pragma unroll
      for (int mi = 0; mi < 4; ++mi)
        af[mi] = *(const bf16x8*)(As + (wr + mi * 16 + l16) * 32 + quad * 8);
#pragma unroll
      for (int ni = 0; ni < 4; ++ni)
        bfr[ni] = *(const bf16x8*)(Bs + (wc + ni * 16 + l16) * 32 + quad * 8);
#pragma unroll
      for (int mi = 0; mi < 4; ++mi)
#pragma unroll
        for (int ni = 0; ni < 4; ++ni)
          acc[mi][ni] = __builtin_amdgcn_mfma_f32_16x16x32_bf16(
              af[mi], bfr[ni], acc[mi][ni], 0, 0, 0);
      __syncthreads();
    }
  }
  size_t hrow = (((size_t)b * HP + (h + 1)) * WP + (w0 + 1)) * 128;
#pragma unroll
  for (int ni = 0; ni < 4; ++ni) {
    int n = wc + ni * 16 + l16;
    float sc = bnss[n], sh = bnss[128 + n];
#pragma unroll
    for (int mi = 0; mi < 4; ++mi)
#pragma unroll
      for (int r = 0; r < 4; ++r) {
        int m = wr + mi * 16 + quad * 4 + r;
        float v = fmaf(acc[mi][ni][r], sc, sh);
        hb[hrow + (size_t)m * 128 + n] = f2bf(fmaxf(v, 0.f));
      }
  }
}

// ---------- conv2: 3x3 128->9 (N padded to 16) + bias + sigmoid ----------
// BM=256 (full row), BN=16, BK=32, 36 K-iters; gates planar [B][9][PIX]
__global__ __launch_bounds__(256) void k_conv2(
    const unsigned short* __restrict__ hb,   // [B][HP][WP][128] bf16
    const unsigned short* __restrict__ w2r,  // [9][4][16][32]   bf16
    const float* __restrict__ bg2,
    float* __restrict__ gates) {
  __shared__ __align__(16) unsigned short As[256 * 32];
  __shared__ __align__(16) unsigned short Bs[16 * 32];
  int tid = threadIdx.x;
  int blk = blockIdx.x;                      // b*256 + h
  int h = blk & 255, b = blk >> 8;
  int wave = tid >> 6, lane = tid & 63;
  int quad = lane >> 4, l16 = lane & 15;

  const floatx4 z4 = {0.f, 0.f, 0.f, 0.f};
  floatx4 acc[4];
#pragma unroll
  for (int i = 0; i < 4; ++i) acc[i] = z4;

  for (int t = 0; t < 9; ++t) {
    int dy = t / 3 - 1, dx = t % 3 - 1;
    const unsigned short* arow =
        hb + (((size_t)b * HP + (h + 1 + dy)) * WP + (1 + dx)) * 128;
    for (int ck = 0; ck < 4; ++ck) {
      const char* asrc = (const char*)(arow + ck * 32);
#pragma unroll
      for (int i = 0; i < 4; ++i) {
        int s = tid + i * 256;
        gl_lds16(asrc + (s >> 2) * 256 + (s & 3) * 16, (char*)As + s * 16);
      }
      if (tid < 64) {
        const char* bsrc = (const char*)(w2r + (((size_t)t * 4 + ck) << 9));
        gl_lds16(bsrc + tid * 16, (char*)Bs + tid * 16);
      }
      __syncthreads();
      bf16x8 bfr = *(const bf16x8*)(Bs + l16 * 32 + quad * 8);
#pragma unroll
      for (int mi = 0; mi < 4; ++mi) {
        bf16x8 af = *(const bf16x8*)(As + (wave * 64 + mi * 16 + l16) * 32 + quad * 8);
        acc[mi] = __builtin_amdgcn_mfma_f32_16x16x32_bf16(af, bfr, acc[mi], 0, 0, 0);
      }
      __syncthreads();
    }
  }
  if (l16 < 9) {
    float bias = bg2[l16];
    size_t gbase = ((size_t)b * 9 + l16) * PIX + h * 256;
#pragma unroll
    for (int mi = 0; mi < 4; ++mi)
#pragma unroll
      for (int r = 0; r < 4; ++r) {
        int m = wave * 64 + mi * 16 + quad * 4 + r;
        float v = acc[mi][r] + bias;
        gates[gbase + m] = 1.f / (1.f + __expf(-v));
      }
  }
}

// ---------- propagation iteration ----------
__global__ __launch_bounds__(256) void k_prop(
    const float* __restrict__ gates, const float* __restrict__ rin,
    float* __restrict__ rout, int final_) {
  int i = blockIdx.x * 256 + threadIdx.x;    // b*PIX + p
  int b = i >> 16, p = i & 65535;
  int h = p >> 8, w = p & 255;
  const float* g = gates + (size_t)b * 9 * PIX + p;
  const float* r = rin + (size_t)b * PIX;
  const int DY[9] = {-1, -1, 0, 1, 1, 1, 0, -1, 0};
  const int DX[9] = {0, 1, 1, 1, 0, -1, -1, -1, 0};
  float deg = 0.f, agg = 0.f;
#pragma unroll
  for (int d = 0; d < 9; ++d) {
    float gd = g[(size_t)d * PIX];
    deg += gd;
    int hh = h - DY[d], ww = w - DX[d];
    float rv = (hh >= 0 && hh < 256 && ww >= 0 && ww < 256) ? r[hh * 256 + ww] : 0.f;
    agg = fmaf(gd, rv, agg);
  }
  float rv = 0.3f * r[p] + 0.7f * agg / (deg + 1e-6f);
  if (final_) rv = fminf(fmaxf(rv, 0.f), 1.f);
  rout[i] = rv;
}

extern "C" void kernel_launch(void* const* d_in, const int* in_sizes, int n_in,
                              void* d_out, int out_size, void* d_ws, size_t ws_size,
                              hipStream_t stream) {
  const float* x     = (const float*)d_in[0];
  const float* y     = (const float*)d_in[1];
  const float* Wx    = (const float*)d_in[2];
  const float* Wy    = (const float*)d_in[3];
  const float* Wg1   = (const float*)d_in[4];
  const float* gamma = (const float*)d_in[5];
  const float* beta  = (const float*)d_in[6];
  const float* mean  = (const float*)d_in[7];
  const float* var   = (const float*)d_in[8];
  const float* Wg2   = (const float*)d_in[9];
  const float* bg2   = (const float*)d_in[10];

  char* ws = (char*)d_ws;
  size_t o = 0;
  auto alloc = [&](size_t sz) { char* p = ws + o; o += (sz + 255) & ~(size_t)255; return p; };
  unsigned short* gi    = (unsigned short*)alloc((size_t)B_ * HP * WP * 256 * 2);  // 272.6 MB
  unsigned short* hb    = (unsigned short*)alloc((size_t)B_ * HP * WP * 128 * 2);  // 136.3 MB
  float*          gates = (float*)alloc((size_t)B_ * 9 * PIX * 4);                 // 18.9 MB
  float*          r0    = (float*)alloc((size_t)B_ * PIX * 4);
  float*          r1    = (float*)alloc((size_t)B_ * PIX * 4);
  unsigned short* w1r   = (unsigned short*)alloc(294912 * 2);
  unsigned short* w2r   = (unsigned short*)alloc(18432 * 2);
  float*          bnss  = (float*)alloc(256 * 4);
  float*          WxT   = (float*)alloc(4096 * 4);
  float*          WyT   = (float*)alloc(4096 * 4);

  hipLaunchKernelGGL(k_prep_w1, dim3(1152), dim3(256), 0, stream, Wg1, w1r);
  hipLaunchKernelGGL(k_prep_w2, dim3(72), dim3(256), 0, stream, Wg2, w2r);
  hipLaunchKernelGGL(k_prep_misc, dim3(33), dim3(256), 0, stream,
                     Wx, Wy, gamma, beta, mean, var, WxT, WyT, bnss);
  hipLaunchKernelGGL(k_zero_border, dim3((8 * 1028 * 192 + 255) / 256), dim3(256), 0, stream,
                     (unsigned int*)gi, (unsigned int*)hb);
  hipLaunchKernelGGL(k_embed, dim3(2048), dim3(256), 0, stream,
                     x, y, WxT, WyT, (unsigned int*)gi, r0);
  hipLaunchKernelGGL(k_conv1, dim3(4096), dim3(256), 0, stream, gi, w1r, bnss, hb);
  hipLaunchKernelGGL(k_conv2, dim3(2048), dim3(256), 0, stream, hb, w2r, bg2, gates);
  hipLaunchKernelGGL(k_prop, dim3(2048), dim3(256), 0, stream, gates, r0, r1, 0);
  hipLaunchKernelGGL(k_prop, dim3(2048), dim3(256), 0, stream, gates, r1, (float*)d_out, 1);
}

// Round 2
// 2463.565 us; speedup vs baseline: 2.0418x; 2.0418x over previous
//
#include <hip/hip_runtime.h>
#include <cstdint>

#define B_  8
#define HH  256
#define WW  256
#define HP  258
#define WP  258
#define PIX (HH*WW)

using bf16x8  = __attribute__((ext_vector_type(8))) short;
using floatx4 = __attribute__((ext_vector_type(4))) float;

__device__ __forceinline__ unsigned short f2bf(float f) {
  union { float f; unsigned u; } v; v.f = f;
  unsigned r = v.u + 0x7FFFu + ((v.u >> 16) & 1u);   // RNE
  return (unsigned short)(r >> 16);
}

__device__ __forceinline__ void gl_lds16(const void* g, void* l) {
  __builtin_amdgcn_global_load_lds(
      (const __attribute__((address_space(1))) void*)g,
      (__attribute__((address_space(3))) void*)l, 16, 0, 0);
}

// ---------- weight prep ----------
// w1r[t][ck][n][kk] = bf16(Wg1[n][ck*32+kk][kh][kw]), t = kh*3+kw
__global__ __launch_bounds__(256) void k_prep_w1(const float* __restrict__ Wg1,
                                                 unsigned short* __restrict__ w1r) {
  int i = blockIdx.x * 256 + threadIdx.x;
  if (i >= 9 * 8 * 128 * 32) return;
  int kk = i & 31, n = (i >> 5) & 127, ck = (i >> 12) & 7, t = i >> 15;
  int c = ck * 32 + kk, kh = t / 3, kw = t - kh * 3;
  w1r[i] = f2bf(Wg1[((n * 256 + c) * 3 + kh) * 3 + kw]);
}

// w2r[t][ck][n(16)][kk] ; n>=9 zero-padded
__global__ __launch_bounds__(256) void k_prep_w2(const float* __restrict__ Wg2,
                                                 unsigned short* __restrict__ w2r) {
  int i = blockIdx.x * 256 + threadIdx.x;
  if (i >= 9 * 4 * 16 * 32) return;
  int kk = i & 31, n = (i >> 5) & 15, ck = (i >> 9) & 3, t = i >> 11;
  int c = ck * 32 + kk, kh = t / 3, kw = t - kh * 3;
  float v = (n < 9) ? Wg2[((n * 128 + c) * 3 + kh) * 3 + kw] : 0.f;
  w2r[i] = f2bf(v);
}

// WxT/WyT transposed fp32 (for scalar-load-friendly embed), BN scale/shift
__global__ __launch_bounds__(256) void k_prep_misc(
    const float* __restrict__ Wx, const float* __restrict__ Wy,
    const float* __restrict__ gamma, const float* __restrict__ beta,
    const float* __restrict__ mean, const float* __restrict__ var,
    float* __restrict__ WxT, float* __restrict__ WyT, float* __restrict__ bnss) {
  int i = blockIdx.x * 256 + threadIdx.x;
  if (i < 4096) { WxT[i] = Wx[(i & 63) * 64 + (i >> 6)]; return; }
  if (i < 8192) { int j = i - 4096; WyT[j] = Wy[(j & 63) * 64 + (j >> 6)]; return; }
  if (i < 8320) {
    int n = i - 8192;
    float sc = gamma[n] * rsqrtf(var[n] + 1e-5f);
    bnss[n] = sc; bnss[128 + n] = beta[n] - mean[n] * sc;
  }
}

// zero 1-px borders of padded gi (256ch) and h (128ch); uint = 2 bf16
__global__ __launch_bounds__(256) void k_zero_border(unsigned int* __restrict__ gi32,
                                                     unsigned int* __restrict__ h32) {
  int i = blockIdx.x * 256 + threadIdx.x;
  if (i >= 8 * 1028 * 192) return;
  int slot = i % 192;
  int pidx = i / 192;
  int b = pidx / 1028;
  int p = pidx - b * 1028;
  int hp, wp;
  if (p < 258)      { hp = 0;           wp = p; }
  else if (p < 516) { hp = 257;         wp = p - 258; }
  else if (p < 772) { hp = p - 516 + 1; wp = 0; }
  else              { hp = p - 772 + 1; wp = 257; }
  size_t pix = ((size_t)b * HP + hp) * WP + wp;
  if (slot < 128) gi32[pix * 128 + slot] = 0u;
  else            h32[pix * 64 + (slot - 128)] = 0u;
}

// ---------- embeddings: 1x1 convs, l2norm, r0, gi = [xn|yn||xn-yn||xn*yn] ----------
// One block = one (b,h) row, one thread = one pixel. Loads: lane-coalesced dword.
// Stores: round-trip through padded LDS, write out as lane-coalesced dwordx4.
__global__ __launch_bounds__(256) void k_embed(
    const float* __restrict__ x, const float* __restrict__ y,
    const float* __restrict__ WxT, const float* __restrict__ WyT,
    unsigned int* __restrict__ gi32, float* __restrict__ r0) {
  __shared__ __align__(16) unsigned int stage[256 * 33];  // +1 pad: 2-way max (free)
  int blk = blockIdx.x;            // b*256 + h
  int b = blk >> 8, h = blk & 255, w = threadIdx.x;
  size_t base = ((size_t)b * 64) * PIX + h * 256 + w;

  float xe[64];
#pragma unroll
  for (int e = 0; e < 64; ++e) xe[e] = 0.f;
#pragma unroll
  for (int c = 0; c < 64; ++c) {
    float xc = x[base + (size_t)c * PIX];
    const float* wr = WxT + c * 64;
#pragma unroll
    for (int e = 0; e < 64; ++e) xe[e] = fmaf(wr[e], xc, xe[e]);
  }
  float ye[64];
#pragma unroll
  for (int e = 0; e < 64; ++e) ye[e] = 0.f;
#pragma unroll
  for (int c = 0; c < 64; ++c) {
    float yc = y[base + (size_t)c * PIX];
    const float* wr = WyT + c * 64;
#pragma unroll
    for (int e = 0; e < 64; ++e) ye[e] = fmaf(wr[e], yc, ye[e]);
  }
  float sx = 0.f, sy = 0.f, sxy = 0.f;
#pragma unroll
  for (int e = 0; e < 64; ++e) {
    sx = fmaf(xe[e], xe[e], sx);
    sy = fmaf(ye[e], ye[e], sy);
    sxy = fmaf(xe[e], ye[e], sxy);
  }
  float inx = 1.f / (sqrtf(sx) + 1e-6f);
  float iny = 1.f / (sqrtf(sy) + 1e-6f);
  r0[b * PIX + h * 256 + w] = (sxy * inx * iny + 1.f) * 0.5f;
#pragma unroll
  for (int e = 0; e < 64; ++e) { xe[e] *= inx; ye[e] *= iny; }

  // gi row base (uint index) for pixel w=0 of this row
  size_t rowbase = (((size_t)b * HP + (h + 1)) * WP + 1) * 128;
#pragma unroll
  for (int c = 0; c < 4; ++c) {
    // pack this chunk's 32 uints (64 bf16) into LDS
#pragma unroll
    for (int j = 0; j < 32; ++j) {
      int e = j * 2;
      float v0, v1;
      if (c == 0)      { v0 = xe[e];                 v1 = xe[e + 1]; }
      else if (c == 1) { v0 = ye[e];                 v1 = ye[e + 1]; }
      else if (c == 2) { v0 = fabsf(xe[e] - ye[e]);  v1 = fabsf(xe[e + 1] - ye[e + 1]); }
      else             { v0 = xe[e] * ye[e];         v1 = xe[e + 1] * ye[e + 1]; }
      stage[w * 33 + j] = (unsigned)f2bf(v0) | ((unsigned)f2bf(v1) << 16);
    }
    __syncthreads();
    // cooperative coalesced write: 8192 uints, 16 B per thread-iter
#pragma unroll
    for (int i = 0; i < 8; ++i) {
      int g = i * 1024 + threadIdx.x * 4;
      int p = g >> 5, u = g & 31;
      uint4 v;
      v.x = stage[p * 33 + u];
      v.y = stage[p * 33 + u + 1];
      v.z = stage[p * 33 + u + 2];
      v.w = stage[p * 33 + u + 3];
      *(uint4*)(gi32 + rowbase + (size_t)p * 128 + c * 32 + u) = v;
    }
    __syncthreads();
  }
}

// ---------- conv1: 3x3 256->128 implicit-GEMM + BN + ReLU ----------
// BM=128 (pixels along W), BN=128, BK=32, 9 taps * 8 chunks = 72 K-iters
__global__ __launch_bounds__(256) void k_conv1(
    const unsigned short* __restrict__ gi,   // [B][HP][WP][256] bf16
    const unsigned short* __restrict__ w1r,  // [9][8][128][32]  bf16
    const float* __restrict__ bnss,
    unsigned short* __restrict__ hb) {       // [B][HP][WP][128] bf16
  __shared__ __align__(16) unsigned short As[128 * 32];
  __shared__ __align__(16) unsigned short Bs[128 * 32];
  int tid = threadIdx.x;
  int blk = blockIdx.x;                      // b*512 + h*2 + wt
  int wt = blk & 1, h = (blk >> 1) & 255, b = blk >> 9;
  int w0 = wt << 7;
  int wave = tid >> 6, lane = tid & 63;
  int wr = (wave >> 1) * 64, wc = (wave & 1) * 64;
  int quad = lane >> 4, l16 = lane & 15;

  const floatx4 z4 = {0.f, 0.f, 0.f, 0.f};
  floatx4 acc[4][4];
#pragma unroll
  for (int i = 0; i < 4; ++i)
#pragma unroll
    for (int j = 0; j < 4; ++j) acc[i][j] = z4;

  for (int t = 0; t < 9; ++t) {
    int dy = t / 3 - 1, dx = t % 3 - 1;
    const unsigned short* arow =
        gi + (((size_t)b * HP + (h + 1 + dy)) * WP + (w0 + 1 + dx)) * 256;
    for (int ck = 0; ck < 8; ++ck) {
      const char* asrc = (const char*)(arow + ck * 32);
      const char* bsrc = (const char*)(w1r + (((size_t)t * 8 + ck) << 12));
      int s0 = tid, s1 = tid + 256;
      gl_lds16(asrc + (s0 >> 2) * 512 + (s0 & 3) * 16, (char*)As + s0 * 16);
      gl_lds16(asrc + (s1 >> 2) * 512 + (s1 & 3) * 16, (char*)As + s1 * 16);
      gl_lds16(bsrc + tid * 16,        (char*)Bs + tid * 16);
      gl_lds16(bsrc + tid * 16 + 4096, (char*)Bs + tid * 16 + 4096);
      __syncthreads();
      bf16x8 af[4], bfr[4];
#pragma unroll
      for (int mi = 0; mi < 4; ++mi)
        af[mi] = *(const bf16x8*)(As + (wr + mi * 16 + l16) * 32 + quad * 8);
#pragma unroll
      for (int ni = 0; ni < 4; ++ni)
        bfr[ni] = *(const bf16x8*)(Bs + (wc + ni * 16 + l16) * 32 + quad * 8);
#pragma unroll
      for (int mi = 0; mi < 4; ++mi)
#pragma unroll
        for (int ni = 0; ni < 4; ++ni)
          acc[mi][ni] = __builtin_amdgcn_mfma_f32_16x16x32_bf16(
              af[mi], bfr[ni], acc[mi][ni], 0, 0, 0);
      __syncthreads();
    }
  }
  size_t hrow = (((size_t)b * HP + (h + 1)) * WP + (w0 + 1)) * 128;
#pragma unroll
  for (int ni = 0; ni < 4; ++ni) {
    int n = wc + ni * 16 + l16;
    float sc = bnss[n], sh = bnss[128 + n];
#pragma unroll
    for (int mi = 0; mi < 4; ++mi)
#pragma unroll
      for (int r = 0; r < 4; ++r) {
        int m = wr + mi * 16 + quad * 4 + r;
        float v = fmaf(acc[mi][ni][r], sc, sh);
        hb[hrow + (size_t)m * 128 + n] = f2bf(fmaxf(v, 0.f));
      }
  }
}

// ---------- conv2: 3x3 128->9 (N padded to 16) + bias + sigmoid ----------
// BM=256 (full row), BN=16, BK=32, 36 K-iters; gates planar [B][9][PIX]
__global__ __launch_bounds__(256) void k_conv2(
    const unsigned short* __restrict__ hb,   // [B][HP][WP][128] bf16
    const unsigned short* __restrict__ w2r,  // [9][4][16][32]   bf16
    const float* __restrict__ bg2,
    float* __restrict__ gates) {
  __shared__ __align__(16) unsigned short As[256 * 32];
  __shared__ __align__(16) unsigned short Bs[16 * 32];
  int tid = threadIdx.x;
  int blk = blockIdx.x;                      // b*256 + h
  int h = blk & 255, b = blk >> 8;
  int wave = tid >> 6, lane = tid & 63;
  int quad = lane >> 4, l16 = lane & 15;

  const floatx4 z4 = {0.f, 0.f, 0.f, 0.f};
  floatx4 acc[4];
#pragma unroll
  for (int i = 0; i < 4; ++i) acc[i] = z4;

  for (int t = 0; t < 9; ++t) {
    int dy = t / 3 - 1, dx = t % 3 - 1;
    const unsigned short* arow =
        hb + (((size_t)b * HP + (h + 1 + dy)) * WP + (1 + dx)) * 128;
    for (int ck = 0; ck < 4; ++ck) {
      const char* asrc = (const char*)(arow + ck * 32);
#pragma unroll
      for (int i = 0; i < 4; ++i) {
        int s = tid + i * 256;
        gl_lds16(asrc + (s >> 2) * 256 + (s & 3) * 16, (char*)As + s * 16);
      }
      if (tid < 64) {
        const char* bsrc = (const char*)(w2r + (((size_t)t * 4 + ck) << 9));
        gl_lds16(bsrc + tid * 16, (char*)Bs + tid * 16);
      }
      __syncthreads();
      bf16x8 bfr = *(const bf16x8*)(Bs + l16 * 32 + quad * 8);
#pragma unroll
      for (int mi = 0; mi < 4; ++mi) {
        bf16x8 af = *(const bf16x8*)(As + (wave * 64 + mi * 16 + l16) * 32 + quad * 8);
        acc[mi] = __builtin_amdgcn_mfma_f32_16x16x32_bf16(af, bfr, acc[mi], 0, 0, 0);
      }
      __syncthreads();
    }
  }
  if (l16 < 9) {
    float bias = bg2[l16];
    size_t gbase = ((size_t)b * 9 + l16) * PIX + h * 256;
#pragma unroll
    for (int mi = 0; mi < 4; ++mi)
#pragma unroll
      for (int r = 0; r < 4; ++r) {
        int m = wave * 64 + mi * 16 + quad * 4 + r;
        float v = acc[mi][r] + bias;
        gates[gbase + m] = 1.f / (1.f + __expf(-v));
      }
  }
}

// ---------- propagation iteration ----------
__global__ __launch_bounds__(256) void k_prop(
    const float* __restrict__ gates, const float* __restrict__ rin,
    float* __restrict__ rout, int final_) {
  int i = blockIdx.x * 256 + threadIdx.x;    // b*PIX + p
  int b = i >> 16, p = i & 65535;
  int h = p >> 8, w = p & 255;
  const float* g = gates + (size_t)b * 9 * PIX + p;
  const float* r = rin + (size_t)b * PIX;
  const int DY[9] = {-1, -1, 0, 1, 1, 1, 0, -1, 0};
  const int DX[9] = {0, 1, 1, 1, 0, -1, -1, -1, 0};
  float deg = 0.f, agg = 0.f;
#pragma unroll
  for (int d = 0; d < 9; ++d) {
    float gd = g[(size_t)d * PIX];
    deg += gd;
    int hh = h - DY[d], ww = w - DX[d];
    float rv = (hh >= 0 && hh < 256 && ww >= 0 && ww < 256) ? r[hh * 256 + ww] : 0.f;
    agg = fmaf(gd, rv, agg);
  }
  float rv = 0.3f * r[p] + 0.7f * agg / (deg + 1e-6f);
  if (final_) rv = fminf(fmaxf(rv, 0.f), 1.f);
  rout[i] = rv;
}

extern "C" void kernel_launch(void* const* d_in, const int* in_sizes, int n_in,
                              void* d_out, int out_size, void* d_ws, size_t ws_size,
                              hipStream_t stream) {
  const float* x     = (const float*)d_in[0];
  const float* y     = (const float*)d_in[1];
  const float* Wx    = (const float*)d_in[2];
  const float* Wy    = (const float*)d_in[3];
  const float* Wg1   = (const float*)d_in[4];
  const float* gamma = (const float*)d_in[5];
  const float* beta  = (const float*)d_in[6];
  const float* mean  = (const float*)d_in[7];
  const float* var   = (const float*)d_in[8];
  const float* Wg2   = (const float*)d_in[9];
  const float* bg2   = (const float*)d_in[10];

  char* ws = (char*)d_ws;
  size_t o = 0;
  auto alloc = [&](size_t sz) { char* p = ws + o; o += (sz + 255) & ~(size_t)255; return p; };
  unsigned short* gi    = (unsigned short*)alloc((size_t)B_ * HP * WP * 256 * 2);  // 272.6 MB
  unsigned short* hb    = (unsigned short*)alloc((size_t)B_ * HP * WP * 128 * 2);  // 136.3 MB
  float*          gates = (float*)alloc((size_t)B_ * 9 * PIX * 4);                 // 18.9 MB
  float*          r0    = (float*)alloc((size_t)B_ * PIX * 4);
  float*          r1    = (float*)alloc((size_t)B_ * PIX * 4);
  unsigned short* w1r   = (unsigned short*)alloc(294912 * 2);
  unsigned short* w2r   = (unsigned short*)alloc(18432 * 2);
  float*          bnss  = (float*)alloc(256 * 4);
  float*          WxT   = (float*)alloc(4096 * 4);
  float*          WyT   = (float*)alloc(4096 * 4);

  hipLaunchKernelGGL(k_prep_w1, dim3(1152), dim3(256), 0, stream, Wg1, w1r);
  hipLaunchKernelGGL(k_prep_w2, dim3(72), dim3(256), 0, stream, Wg2, w2r);
  hipLaunchKernelGGL(k_prep_misc, dim3(33), dim3(256), 0, stream,
                     Wx, Wy, gamma, beta, mean, var, WxT, WyT, bnss);
  hipLaunchKernelGGL(k_zero_border, dim3((8 * 1028 * 192 + 255) / 256), dim3(256), 0, stream,
                     (unsigned int*)gi, (unsigned int*)hb);
  hipLaunchKernelGGL(k_embed, dim3(2048), dim3(256), 0, stream,
                     x, y, WxT, WyT, (unsigned int*)gi, r0);
  hipLaunchKernelGGL(k_conv1, dim3(4096), dim3(256), 0, stream, gi, w1r, bnss, hb);
  hipLaunchKernelGGL(k_conv2, dim3(2048), dim3(256), 0, stream, hb, w2r, bg2, gates);
  hipLaunchKernelGGL(k_prop, dim3(2048), dim3(256), 0, stream, gates, r0, r1, 0);
  hipLaunchKernelGGL(k_prop, dim3(2048), dim3(256), 0, stream, gates, r1, (float*)d_out, 1);
}

// Round 3
// 984.820 us; speedup vs baseline: 5.1076x; 2.5015x over previous
//
#include <hip/hip_runtime.h>
#include <cstdint>

#define B_  8
#define HH  256
#define WW  256
#define HP  258
#define WP  258
#define PIX (HH*WW)

using bf16x8   = __attribute__((ext_vector_type(8))) short;
using floatx4  = __attribute__((ext_vector_type(4))) float;
using floatx16 = __attribute__((ext_vector_type(16))) float;

__device__ __forceinline__ unsigned short f2bf(float f) {
  union { float f; unsigned u; } v; v.f = f;
  unsigned r = v.u + 0x7FFFu + ((v.u >> 16) & 1u);   // RNE
  return (unsigned short)(r >> 16);
}
__device__ __forceinline__ unsigned pk2(float a, float b) {
  return (unsigned)f2bf(a) | ((unsigned)f2bf(b) << 16);
}

__device__ __forceinline__ void gl_lds16(const void* g, void* l) {
  __builtin_amdgcn_global_load_lds(
      (const __attribute__((address_space(1))) void*)g,
      (__attribute__((address_space(3))) void*)l, 16, 0, 0);
}

// ---------- weight prep ----------
// w1r[t][ck][n][kk] = bf16(Wg1[n][ck*32+kk][kh][kw]), t = kh*3+kw
__global__ __launch_bounds__(256) void k_prep_w1(const float* __restrict__ Wg1,
                                                 unsigned short* __restrict__ w1r) {
  int i = blockIdx.x * 256 + threadIdx.x;
  if (i >= 9 * 8 * 128 * 32) return;
  int kk = i & 31, n = (i >> 5) & 127, ck = (i >> 12) & 7, t = i >> 15;
  int c = ck * 32 + kk, kh = t / 3, kw = t - kh * 3;
  w1r[i] = f2bf(Wg1[((n * 256 + c) * 3 + kh) * 3 + kw]);
}

// w2r[t][ck][n(16)][kk] ; n>=9 zero-padded
__global__ __launch_bounds__(256) void k_prep_w2(const float* __restrict__ Wg2,
                                                 unsigned short* __restrict__ w2r) {
  int i = blockIdx.x * 256 + threadIdx.x;
  if (i >= 9 * 4 * 16 * 32) return;
  int kk = i & 31, n = (i >> 5) & 15, ck = (i >> 9) & 3, t = i >> 11;
  int c = ck * 32 + kk, kh = t / 3, kw = t - kh * 3;
  float v = (n < 9) ? Wg2[((n * 128 + c) * 3 + kh) * 3 + kw] : 0.f;
  w2r[i] = f2bf(v);
}

// embed weights in 32x32x16 A-fragment order:
// wemb[g][mt][ks][lane][j] = bf16(Wg[e = 32*mt + (lane&31)][c = (lane>>5)*8 + j + 16*ks])
__global__ __launch_bounds__(256) void k_prep_wemb(const float* __restrict__ Wx,
                                                   const float* __restrict__ Wy,
                                                   unsigned short* __restrict__ wemb) {
  int i = blockIdx.x * 256 + threadIdx.x;
  if (i >= 8192) return;
  int j = i & 7, lane = (i >> 3) & 63, ks = (i >> 9) & 3, mt = (i >> 11) & 1, g = i >> 12;
  int e = mt * 32 + (lane & 31);
  int c = (lane >> 5) * 8 + j + ks * 16;
  const float* src = g ? Wy : Wx;
  wemb[i] = f2bf(src[e * 64 + c]);
}

// BN scale/shift
__global__ __launch_bounds__(256) void k_prep_bn(
    const float* __restrict__ gamma, const float* __restrict__ beta,
    const float* __restrict__ mean, const float* __restrict__ var,
    float* __restrict__ bnss) {
  int n = threadIdx.x;
  if (n >= 128) return;
  float sc = gamma[n] * rsqrtf(var[n] + 1e-5f);
  bnss[n] = sc; bnss[128 + n] = beta[n] - mean[n] * sc;
}

// zero 1-px borders of padded gi (256ch) and h (128ch); uint = 2 bf16
__global__ __launch_bounds__(256) void k_zero_border(unsigned int* __restrict__ gi32,
                                                     unsigned int* __restrict__ h32) {
  int i = blockIdx.x * 256 + threadIdx.x;
  if (i >= 8 * 1028 * 192) return;
  int slot = i % 192;
  int pidx = i / 192;
  int b = pidx / 1028;
  int p = pidx - b * 1028;
  int hp, wp;
  if (p < 258)      { hp = 0;           wp = p; }
  else if (p < 516) { hp = 257;         wp = p - 258; }
  else if (p < 772) { hp = p - 516 + 1; wp = 0; }
  else              { hp = p - 772 + 1; wp = 257; }
  size_t pix = ((size_t)b * HP + hp) * WP + wp;
  if (slot < 128) gi32[pix * 128 + slot] = 0u;
  else            h32[pix * 64 + (slot - 128)] = 0u;
}

// ---------- embeddings via MFMA ----------
// Block = 128 px (half row), 4 waves x 32 px. Per wave:
//   xe[64] = Wx(64x64) . x(64 x 32px)  via 2 m-tiles x 4 k-steps of 32x32x16
//   B-frag loads straight from planar fp32 x: two 128B segments per instr.
// D-layout: col(px)=lane&31, row(e)=(reg&3)+8*(reg>>2)+4*(lane>>5)+32*mt.
// Lane pair (l, l^32) holds all 64 e of one px -> shfl_xor(32) for norms.
__global__ __launch_bounds__(256) void k_embed(
    const float* __restrict__ x, const float* __restrict__ y,
    const unsigned short* __restrict__ wemb,
    unsigned int* __restrict__ gi32, float* __restrict__ r0) {
  __shared__ __align__(16) unsigned int stage[128 * 129];  // stride 129: bank step 1/px
  int blk = blockIdx.x;                      // b*512 + h*2 + wt
  int wt = blk & 1, h = (blk >> 1) & 255, b = blk >> 9;
  int w0 = wt << 7;
  int tid = threadIdx.x, wave = tid >> 6, lane = tid & 63;
  int n = lane & 31, kg = lane >> 5;
  int pxl = wave * 32 + n;                   // px within block
  int pxg = w0 + pxl;                        // w coordinate

  floatx16 xacc[2], yacc[2];
#pragma unroll
  for (int mt = 0; mt < 2; ++mt)
#pragma unroll
    for (int r = 0; r < 16; ++r) { xacc[mt][r] = 0.f; yacc[mt][r] = 0.f; }

  const uint4* wq = (const uint4*)wemb;
  size_t pbase = (size_t)kg * 8 * PIX + h * 256 + pxg;

  {  // X GEMM
    const float* src = x + (size_t)b * 64 * PIX + pbase;
    bf16x8 bfrag[4];
#pragma unroll
    for (int ks = 0; ks < 4; ++ks) {
      union { unsigned u[4]; bf16x8 v; } pk;
#pragma unroll
      for (int j = 0; j < 4; ++j)
        pk.u[j] = pk2(src[(size_t)(16 * ks + 2 * j) * PIX],
                      src[(size_t)(16 * ks + 2 * j + 1) * PIX]);
      bfrag[ks] = pk.v;
    }
#pragma unroll
    for (int mt = 0; mt < 2; ++mt)
#pragma unroll
      for (int ks = 0; ks < 4; ++ks) {
        union { uint4 q; bf16x8 v; } wf;
        wf.q = wq[(mt * 4 + ks) * 64 + lane];
        xacc[mt] = __builtin_amdgcn_mfma_f32_32x32x16_bf16(wf.v, bfrag[ks], xacc[mt], 0, 0, 0);
      }
  }
  {  // Y GEMM
    const float* src = y + (size_t)b * 64 * PIX + pbase;
    bf16x8 bfrag[4];
#pragma unroll
    for (int ks = 0; ks < 4; ++ks) {
      union { unsigned u[4]; bf16x8 v; } pk;
#pragma unroll
      for (int j = 0; j < 4; ++j)
        pk.u[j] = pk2(src[(size_t)(16 * ks + 2 * j) * PIX],
                      src[(size_t)(16 * ks + 2 * j + 1) * PIX]);
      bfrag[ks] = pk.v;
    }
#pragma unroll
    for (int mt = 0; mt < 2; ++mt)
#pragma unroll
      for (int ks = 0; ks < 4; ++ks) {
        union { uint4 q; bf16x8 v; } wf;
        wf.q = wq[(8 + mt * 4 + ks) * 64 + lane];
        yacc[mt] = __builtin_amdgcn_mfma_f32_32x32x16_bf16(wf.v, bfrag[ks], yacc[mt], 0, 0, 0);
      }
  }

  // norms + r0 (lane pair holds all 64 e of px)
  float sx = 0.f, sy = 0.f, sxy = 0.f;
#pragma unroll
  for (int mt = 0; mt < 2; ++mt)
#pragma unroll
    for (int r = 0; r < 16; ++r) {
      float xv = xacc[mt][r], yv = yacc[mt][r];
      sx = fmaf(xv, xv, sx); sy = fmaf(yv, yv, sy); sxy = fmaf(xv, yv, sxy);
    }
  sx += __shfl_xor(sx, 32); sy += __shfl_xor(sy, 32); sxy += __shfl_xor(sxy, 32);
  float inx = 1.f / (sqrtf(sx) + 1e-6f);
  float iny = 1.f / (sqrtf(sy) + 1e-6f);
  if (kg == 0) r0[b * PIX + h * 256 + pxg] = (sxy * inx * iny + 1.f) * 0.5f;

  // pack gi row [xn|yn||xn-yn||xn*yn] into LDS stage, single pass
#pragma unroll
  for (int mt = 0; mt < 2; ++mt)
#pragma unroll
    for (int g = 0; g < 4; ++g) {
      int e0 = 32 * mt + 8 * g + 4 * kg;
      unsigned* row = stage + pxl * 129 + (e0 >> 1);
      float a0 = xacc[mt][4*g]   * inx, a1 = xacc[mt][4*g+1] * inx;
      float a2 = xacc[mt][4*g+2] * inx, a3 = xacc[mt][4*g+3] * inx;
      float b0 = yacc[mt][4*g]   * iny, b1 = yacc[mt][4*g+1] * iny;
      float b2 = yacc[mt][4*g+2] * iny, b3 = yacc[mt][4*g+3] * iny;
      row[0]      = pk2(a0, a1);                    row[1]      = pk2(a2, a3);
      row[32]     = pk2(b0, b1);                    row[33]     = pk2(b2, b3);
      row[64]     = pk2(fabsf(a0-b0), fabsf(a1-b1)); row[65]    = pk2(fabsf(a2-b2), fabsf(a3-b3));
      row[96]     = pk2(a0*b0, a1*b1);              row[97]     = pk2(a2*b2, a3*b3);
    }
  __syncthreads();

  // coalesced flush: 128 rows x 128 uints
  size_t rowbase = (((size_t)b * HP + (h + 1)) * WP + (w0 + 1)) * 128;
#pragma unroll
  for (int i = 0; i < 16; ++i) {
    int gg = i * 1024 + tid * 4;
    int p = gg >> 7, u = gg & 127;
    const unsigned* s = stage + p * 129 + u;
    uint4 v; v.x = s[0]; v.y = s[1]; v.z = s[2]; v.w = s[3];
    *(uint4*)(gi32 + rowbase + (size_t)p * 128 + u) = v;
  }
}

// ---------- conv1: 3x3 256->128 implicit-GEMM + BN + ReLU ----------
__global__ __launch_bounds__(256) void k_conv1(
    const unsigned short* __restrict__ gi,   // [B][HP][WP][256] bf16
    const unsigned short* __restrict__ w1r,  // [9][8][128][32]  bf16
    const float* __restrict__ bnss,
    unsigned short* __restrict__ hb) {       // [B][HP][WP][128] bf16
  __shared__ __align__(16) unsigned short As[128 * 32];
  __shared__ __align__(16) unsigned short Bs[128 * 32];
  int tid = threadIdx.x;
  int blk = blockIdx.x;                      // b*512 + h*2 + wt
  int wt = blk & 1, h = (blk >> 1) & 255, b = blk >> 9;
  int w0 = wt << 7;
  int wave = tid >> 6, lane = tid & 63;
  int wr = (wave >> 1) * 64, wc = (wave & 1) * 64;
  int quad = lane >> 4, l16 = lane & 15;

  const floatx4 z4 = {0.f, 0.f, 0.f, 0.f};
  floatx4 acc[4][4];
#pragma unroll
  for (int i = 0; i < 4; ++i)
#pragma unroll
    for (int j = 0; j < 4; ++j) acc[i][j] = z4;

  for (int t = 0; t < 9; ++t) {
    int dy = t / 3 - 1, dx = t % 3 - 1;
    const unsigned short* arow =
        gi + (((size_t)b * HP + (h + 1 + dy)) * WP + (w0 + 1 + dx)) * 256;
    for (int ck = 0; ck < 8; ++ck) {
      const char* asrc = (const char*)(arow + ck * 32);
      const char* bsrc = (const char*)(w1r + (((size_t)t * 8 + ck) << 12));
      int s0 = tid, s1 = tid + 256;
      gl_lds16(asrc + (s0 >> 2) * 512 + (s0 & 3) * 16, (char*)As + s0 * 16);
      gl_lds16(asrc + (s1 >> 2) * 512 + (s1 & 3) * 16, (char*)As + s1 * 16);
      gl_lds16(bsrc + tid * 16,        (char*)Bs + tid * 16);
      gl_lds16(bsrc + tid * 16 + 4096, (char*)Bs + tid * 16 + 4096);
      __syncthreads();
      bf16x8 af[4], bfr[4];
#pragma unroll
      for (int mi = 0; mi < 4; ++mi)
        af[mi] = *(const bf16x8*)(As + (wr + mi * 16 + l16) * 32 + quad * 8);
#pragma unroll
      for (int ni = 0; ni < 4; ++ni)
        bfr[ni] = *(const bf16x8*)(Bs + (wc + ni * 16 + l16) * 32 + quad * 8);
#pragma unroll
      for (int mi = 0; mi < 4; ++mi)
#pragma unroll
        for (int ni = 0; ni < 4; ++ni)
          acc[mi][ni] = __builtin_amdgcn_mfma_f32_16x16x32_bf16(
              af[mi], bfr[ni], acc[mi][ni], 0, 0, 0);
      __syncthreads();
    }
  }
  size_t hrow = (((size_t)b * HP + (h + 1)) * WP + (w0 + 1)) * 128;
#pragma unroll
  for (int ni = 0; ni < 4; ++ni) {
    int n = wc + ni * 16 + l16;
    float sc = bnss[n], sh = bnss[128 + n];
#pragma unroll
    for (int mi = 0; mi < 4; ++mi)
#pragma unroll
      for (int r = 0; r < 4; ++r) {
        int m = wr + mi * 16 + quad * 4 + r;
        float v = fmaf(acc[mi][ni][r], sc, sh);
        hb[hrow + (size_t)m * 128 + n] = f2bf(fmaxf(v, 0.f));
      }
  }
}

// ---------- conv2: 3x3 128->9 (N padded to 16) + bias + sigmoid ----------
__global__ __launch_bounds__(256) void k_conv2(
    const unsigned short* __restrict__ hb,   // [B][HP][WP][128] bf16
    const unsigned short* __restrict__ w2r,  // [9][4][16][32]   bf16
    const float* __restrict__ bg2,
    float* __restrict__ gates) {
  __shared__ __align__(16) unsigned short As[256 * 32];
  __shared__ __align__(16) unsigned short Bs[16 * 32];
  int tid = threadIdx.x;
  int blk = blockIdx.x;                      // b*256 + h
  int h = blk & 255, b = blk >> 8;
  int wave = tid >> 6, lane = tid & 63;
  int quad = lane >> 4, l16 = lane & 15;

  const floatx4 z4 = {0.f, 0.f, 0.f, 0.f};
  floatx4 acc[4];
#pragma unroll
  for (int i = 0; i < 4; ++i) acc[i] = z4;

  for (int t = 0; t < 9; ++t) {
    int dy = t / 3 - 1, dx = t % 3 - 1;
    const unsigned short* arow =
        hb + (((size_t)b * HP + (h + 1 + dy)) * WP + (1 + dx)) * 128;
    for (int ck = 0; ck < 4; ++ck) {
      const char* asrc = (const char*)(arow + ck * 32);
#pragma unroll
      for (int i = 0; i < 4; ++i) {
        int s = tid + i * 256;
        gl_lds16(asrc + (s >> 2) * 256 + (s & 3) * 16, (char*)As + s * 16);
      }
      if (tid < 64) {
        const char* bsrc = (const char*)(w2r + (((size_t)t * 4 + ck) << 9));
        gl_lds16(bsrc + tid * 16, (char*)Bs + tid * 16);
      }
      __syncthreads();
      bf16x8 bfr = *(const bf16x8*)(Bs + l16 * 32 + quad * 8);
#pragma unroll
      for (int mi = 0; mi < 4; ++mi) {
        bf16x8 af = *(const bf16x8*)(As + (wave * 64 + mi * 16 + l16) * 32 + quad * 8);
        acc[mi] = __builtin_amdgcn_mfma_f32_16x16x32_bf16(af, bfr, acc[mi], 0, 0, 0);
      }
      __syncthreads();
    }
  }
  if (l16 < 9) {
    float bias = bg2[l16];
    size_t gbase = ((size_t)b * 9 + l16) * PIX + h * 256;
#pragma unroll
    for (int mi = 0; mi < 4; ++mi)
#pragma unroll
      for (int r = 0; r < 4; ++r) {
        int m = wave * 64 + mi * 16 + quad * 4 + r;
        float v = acc[mi][r] + bias;
        gates[gbase + m] = 1.f / (1.f + __expf(-v));
      }
  }
}

// ---------- propagation iteration ----------
__global__ __launch_bounds__(256) void k_prop(
    const float* __restrict__ gates, const float* __restrict__ rin,
    float* __restrict__ rout, int final_) {
  int i = blockIdx.x * 256 + threadIdx.x;    // b*PIX + p
  int b = i >> 16, p = i & 65535;
  int h = p >> 8, w = p & 255;
  const float* g = gates + (size_t)b * 9 * PIX + p;
  const float* r = rin + (size_t)b * PIX;
  const int DY[9] = {-1, -1, 0, 1, 1, 1, 0, -1, 0};
  const int DX[9] = {0, 1, 1, 1, 0, -1, -1, -1, 0};
  float deg = 0.f, agg = 0.f;
#pragma unroll
  for (int d = 0; d < 9; ++d) {
    float gd = g[(size_t)d * PIX];
    deg += gd;
    int hh = h - DY[d], ww = w - DX[d];
    float rv = (hh >= 0 && hh < 256 && ww >= 0 && ww < 256) ? r[hh * 256 + ww] : 0.f;
    agg = fmaf(gd, rv, agg);
  }
  float rv = 0.3f * r[p] + 0.7f * agg / (deg + 1e-6f);
  if (final_) rv = fminf(fmaxf(rv, 0.f), 1.f);
  rout[i] = rv;
}

extern "C" void kernel_launch(void* const* d_in, const int* in_sizes, int n_in,
                              void* d_out, int out_size, void* d_ws, size_t ws_size,
                              hipStream_t stream) {
  const float* x     = (const float*)d_in[0];
  const float* y     = (const float*)d_in[1];
  const float* Wx    = (const float*)d_in[2];
  const float* Wy    = (const float*)d_in[3];
  const float* Wg1   = (const float*)d_in[4];
  const float* gamma = (const float*)d_in[5];
  const float* beta  = (const float*)d_in[6];
  const float* mean  = (const float*)d_in[7];
  const float* var   = (const float*)d_in[8];
  const float* Wg2   = (const float*)d_in[9];
  const float* bg2   = (const float*)d_in[10];

  char* ws = (char*)d_ws;
  size_t o = 0;
  auto alloc = [&](size_t sz) { char* p = ws + o; o += (sz + 255) & ~(size_t)255; return p; };
  unsigned short* gi    = (unsigned short*)alloc((size_t)B_ * HP * WP * 256 * 2);  // 272.6 MB
  unsigned short* hb    = (unsigned short*)alloc((size_t)B_ * HP * WP * 128 * 2);  // 136.3 MB
  float*          gates = (float*)alloc((size_t)B_ * 9 * PIX * 4);                 // 18.9 MB
  float*          r0    = (float*)alloc((size_t)B_ * PIX * 4);
  float*          r1    = (float*)alloc((size_t)B_ * PIX * 4);
  unsigned short* w1r   = (unsigned short*)alloc(294912 * 2);
  unsigned short* w2r   = (unsigned short*)alloc(18432 * 2);
  unsigned short* wemb  = (unsigned short*)alloc(8192 * 2);
  float*          bnss  = (float*)alloc(256 * 4);

  hipLaunchKernelGGL(k_prep_w1, dim3(1152), dim3(256), 0, stream, Wg1, w1r);
  hipLaunchKernelGGL(k_prep_w2, dim3(72), dim3(256), 0, stream, Wg2, w2r);
  hipLaunchKernelGGL(k_prep_wemb, dim3(32), dim3(256), 0, stream, Wx, Wy, wemb);
  hipLaunchKernelGGL(k_prep_bn, dim3(1), dim3(256), 0, stream,
                     gamma, beta, mean, var, bnss);
  hipLaunchKernelGGL(k_zero_border, dim3((8 * 1028 * 192 + 255) / 256), dim3(256), 0, stream,
                     (unsigned int*)gi, (unsigned int*)hb);
  hipLaunchKernelGGL(k_embed, dim3(4096), dim3(256), 0, stream,
                     x, y, wemb, (unsigned int*)gi, r0);
  hipLaunchKernelGGL(k_conv1, dim3(4096), dim3(256), 0, stream, gi, w1r, bnss, hb);
  hipLaunchKernelGGL(k_conv2, dim3(2048), dim3(256), 0, stream, hb, w2r, bg2, gates);
  hipLaunchKernelGGL(k_prop, dim3(2048), dim3(256), 0, stream, gates, r0, r1, 0);
  hipLaunchKernelGGL(k_prop, dim3(2048), dim3(256), 0, stream, gates, r1, (float*)d_out, 1);
}

// Round 4
// 726.698 us; speedup vs baseline: 6.9218x; 1.3552x over previous
//
#include <hip/hip_runtime.h>
#include <cstdint>

#define B_  8
#define HH  256
#define WW  256
#define HP  258
#define WP  258
#define PIX (HH*WW)

using bf16x8   = __attribute__((ext_vector_type(8))) short;
using floatx4  = __attribute__((ext_vector_type(4))) float;
using floatx16 = __attribute__((ext_vector_type(16))) float;

__device__ __forceinline__ unsigned short f2bf(float f) {
  union { float f; unsigned u; } v; v.f = f;
  unsigned r = v.u + 0x7FFFu + ((v.u >> 16) & 1u);   // RNE
  return (unsigned short)(r >> 16);
}
__device__ __forceinline__ unsigned pk2(float a, float b) {
  return (unsigned)f2bf(a) | ((unsigned)f2bf(b) << 16);
}

__device__ __forceinline__ void gl_lds16(const void* g, void* l) {
  __builtin_amdgcn_global_load_lds(
      (const __attribute__((address_space(1))) void*)g,
      (__attribute__((address_space(3))) void*)l, 16, 0, 0);
}

// ---------- weight prep ----------
// w1r[t][ck][n][kk] = bf16(Wg1[n][ck*32+kk][kh][kw]), t = kh*3+kw
__global__ __launch_bounds__(256) void k_prep_w1(const float* __restrict__ Wg1,
                                                 unsigned short* __restrict__ w1r) {
  int i = blockIdx.x * 256 + threadIdx.x;
  if (i >= 9 * 8 * 128 * 32) return;
  int kk = i & 31, n = (i >> 5) & 127, ck = (i >> 12) & 7, t = i >> 15;
  int c = ck * 32 + kk, kh = t / 3, kw = t - kh * 3;
  w1r[i] = f2bf(Wg1[((n * 256 + c) * 3 + kh) * 3 + kw]);
}

// w2r[t][ck][n(16)][kk] ; n>=9 zero-padded
__global__ __launch_bounds__(256) void k_prep_w2(const float* __restrict__ Wg2,
                                                 unsigned short* __restrict__ w2r) {
  int i = blockIdx.x * 256 + threadIdx.x;
  if (i >= 9 * 4 * 16 * 32) return;
  int kk = i & 31, n = (i >> 5) & 15, ck = (i >> 9) & 3, t = i >> 11;
  int c = ck * 32 + kk, kh = t / 3, kw = t - kh * 3;
  float v = (n < 9) ? Wg2[((n * 128 + c) * 3 + kh) * 3 + kw] : 0.f;
  w2r[i] = f2bf(v);
}

// embed weights in 32x32x16 A-fragment order:
// wemb[g][mt][ks][lane][j] = bf16(Wg[e = 32*mt + (lane&31)][c = (lane>>5)*8 + j + 16*ks])
__global__ __launch_bounds__(256) void k_prep_wemb(const float* __restrict__ Wx,
                                                   const float* __restrict__ Wy,
                                                   unsigned short* __restrict__ wemb) {
  int i = blockIdx.x * 256 + threadIdx.x;
  if (i >= 8192) return;
  int j = i & 7, lane = (i >> 3) & 63, ks = (i >> 9) & 3, mt = (i >> 11) & 1, g = i >> 12;
  int e = mt * 32 + (lane & 31);
  int c = (lane >> 5) * 8 + j + ks * 16;
  const float* src = g ? Wy : Wx;
  wemb[i] = f2bf(src[e * 64 + c]);
}

// BN scale/shift
__global__ __launch_bounds__(256) void k_prep_bn(
    const float* __restrict__ gamma, const float* __restrict__ beta,
    const float* __restrict__ mean, const float* __restrict__ var,
    float* __restrict__ bnss) {
  int n = threadIdx.x;
  if (n >= 128) return;
  float sc = gamma[n] * rsqrtf(var[n] + 1e-5f);
  bnss[n] = sc; bnss[128 + n] = beta[n] - mean[n] * sc;
}

// zero 1-px borders of padded gi (256ch) and h (128ch); uint = 2 bf16
__global__ __launch_bounds__(256) void k_zero_border(unsigned int* __restrict__ gi32,
                                                     unsigned int* __restrict__ h32) {
  int i = blockIdx.x * 256 + threadIdx.x;
  if (i >= 8 * 1028 * 192) return;
  int slot = i % 192;
  int pidx = i / 192;
  int b = pidx / 1028;
  int p = pidx - b * 1028;
  int hp, wp;
  if (p < 258)      { hp = 0;           wp = p; }
  else if (p < 516) { hp = 257;         wp = p - 258; }
  else if (p < 772) { hp = p - 516 + 1; wp = 0; }
  else              { hp = p - 772 + 1; wp = 257; }
  size_t pix = ((size_t)b * HP + hp) * WP + wp;
  if (slot < 128) gi32[pix * 128 + slot] = 0u;
  else            h32[pix * 64 + (slot - 128)] = 0u;
}

// ---------- embeddings via MFMA ----------
__global__ __launch_bounds__(256) void k_embed(
    const float* __restrict__ x, const float* __restrict__ y,
    const unsigned short* __restrict__ wemb,
    unsigned int* __restrict__ gi32, float* __restrict__ r0) {
  __shared__ __align__(16) unsigned int stage[128 * 129];  // stride 129: bank step 1/px
  int blk = blockIdx.x;                      // b*512 + h*2 + wt
  int wt = blk & 1, h = (blk >> 1) & 255, b = blk >> 9;
  int w0 = wt << 7;
  int tid = threadIdx.x, wave = tid >> 6, lane = tid & 63;
  int n = lane & 31, kg = lane >> 5;
  int pxl = wave * 32 + n;                   // px within block
  int pxg = w0 + pxl;                        // w coordinate

  floatx16 xacc[2], yacc[2];
#pragma unroll
  for (int mt = 0; mt < 2; ++mt)
#pragma unroll
    for (int r = 0; r < 16; ++r) { xacc[mt][r] = 0.f; yacc[mt][r] = 0.f; }

  const uint4* wq = (const uint4*)wemb;
  size_t pbase = (size_t)kg * 8 * PIX + h * 256 + pxg;

  {  // X GEMM
    const float* src = x + (size_t)b * 64 * PIX + pbase;
    bf16x8 bfrag[4];
#pragma unroll
    for (int ks = 0; ks < 4; ++ks) {
      union { unsigned u[4]; bf16x8 v; } pk;
#pragma unroll
      for (int j = 0; j < 4; ++j)
        pk.u[j] = pk2(src[(size_t)(16 * ks + 2 * j) * PIX],
                      src[(size_t)(16 * ks + 2 * j + 1) * PIX]);
      bfrag[ks] = pk.v;
    }
#pragma unroll
    for (int mt = 0; mt < 2; ++mt)
#pragma unroll
      for (int ks = 0; ks < 4; ++ks) {
        union { uint4 q; bf16x8 v; } wf;
        wf.q = wq[(mt * 4 + ks) * 64 + lane];
        xacc[mt] = __builtin_amdgcn_mfma_f32_32x32x16_bf16(wf.v, bfrag[ks], xacc[mt], 0, 0, 0);
      }
  }
  {  // Y GEMM
    const float* src = y + (size_t)b * 64 * PIX + pbase;
    bf16x8 bfrag[4];
#pragma unroll
    for (int ks = 0; ks < 4; ++ks) {
      union { unsigned u[4]; bf16x8 v; } pk;
#pragma unroll
      for (int j = 0; j < 4; ++j)
        pk.u[j] = pk2(src[(size_t)(16 * ks + 2 * j) * PIX],
                      src[(size_t)(16 * ks + 2 * j + 1) * PIX]);
      bfrag[ks] = pk.v;
    }
#pragma unroll
    for (int mt = 0; mt < 2; ++mt)
#pragma unroll
      for (int ks = 0; ks < 4; ++ks) {
        union { uint4 q; bf16x8 v; } wf;
        wf.q = wq[(8 + mt * 4 + ks) * 64 + lane];
        yacc[mt] = __builtin_amdgcn_mfma_f32_32x32x16_bf16(wf.v, bfrag[ks], yacc[mt], 0, 0, 0);
      }
  }

  // norms + r0 (lane pair holds all 64 e of px)
  float sx = 0.f, sy = 0.f, sxy = 0.f;
#pragma unroll
  for (int mt = 0; mt < 2; ++mt)
#pragma unroll
    for (int r = 0; r < 16; ++r) {
      float xv = xacc[mt][r], yv = yacc[mt][r];
      sx = fmaf(xv, xv, sx); sy = fmaf(yv, yv, sy); sxy = fmaf(xv, yv, sxy);
    }
  sx += __shfl_xor(sx, 32); sy += __shfl_xor(sy, 32); sxy += __shfl_xor(sxy, 32);
  float inx = 1.f / (sqrtf(sx) + 1e-6f);
  float iny = 1.f / (sqrtf(sy) + 1e-6f);
  if (kg == 0) r0[b * PIX + h * 256 + pxg] = (sxy * inx * iny + 1.f) * 0.5f;

  // pack gi row [xn|yn||xn-yn||xn*yn] into LDS stage, single pass
#pragma unroll
  for (int mt = 0; mt < 2; ++mt)
#pragma unroll
    for (int g = 0; g < 4; ++g) {
      int e0 = 32 * mt + 8 * g + 4 * kg;
      unsigned* row = stage + pxl * 129 + (e0 >> 1);
      float a0 = xacc[mt][4*g]   * inx, a1 = xacc[mt][4*g+1] * inx;
      float a2 = xacc[mt][4*g+2] * inx, a3 = xacc[mt][4*g+3] * inx;
      float b0 = yacc[mt][4*g]   * iny, b1 = yacc[mt][4*g+1] * iny;
      float b2 = yacc[mt][4*g+2] * iny, b3 = yacc[mt][4*g+3] * iny;
      row[0]      = pk2(a0, a1);                    row[1]      = pk2(a2, a3);
      row[32]     = pk2(b0, b1);                    row[33]     = pk2(b2, b3);
      row[64]     = pk2(fabsf(a0-b0), fabsf(a1-b1)); row[65]    = pk2(fabsf(a2-b2), fabsf(a3-b3));
      row[96]     = pk2(a0*b0, a1*b1);              row[97]     = pk2(a2*b2, a3*b3);
    }
  __syncthreads();

  // coalesced flush: 128 rows x 128 uints
  size_t rowbase = (((size_t)b * HP + (h + 1)) * WP + (w0 + 1)) * 128;
#pragma unroll
  for (int i = 0; i < 16; ++i) {
    int gg = i * 1024 + tid * 4;
    int p = gg >> 7, u = gg & 127;
    const unsigned* s = stage + p * 129 + u;
    uint4 v; v.x = s[0]; v.y = s[1]; v.z = s[2]; v.w = s[3];
    *(uint4*)(gi32 + rowbase + (size_t)p * 128 + u) = v;
  }
}

// ---------- conv1: 3x3 256->128 implicit-GEMM + BN + ReLU ----------
// Restructured: dy outer; per (dy,ck) stage one 130-px haloed A row + 3 dx
// B tiles; 3 dx taps = 48 MFMA/wave per barrier interval (24 intervals).
// XOR chunk swizzle (slot (c-px)&3, applied at staging source) -> 2-way
// bank access on fragment reads (free).
__global__ __launch_bounds__(256) void k_conv1(
    const unsigned short* __restrict__ gi,   // [B][HP][WP][256] bf16
    const unsigned short* __restrict__ w1r,  // [9][8][128][32]  bf16
    const float* __restrict__ bnss,
    unsigned short* __restrict__ hb) {       // [B][HP][WP][128] bf16
  __shared__ __align__(16) unsigned short As[520 * 8];    // 130 px x 32 ch = 8320 B
  __shared__ __align__(16) unsigned short Bs[1536 * 8];   // 3 x (128 x 32) = 24576 B
  int tid = threadIdx.x;
  int blk = blockIdx.x;                      // b*512 + h*2 + wt
  int wt = blk & 1, h = (blk >> 1) & 255, b = blk >> 9;
  int w0 = wt << 7;
  int wave = tid >> 6, lane = tid & 63;
  int wr = (wave >> 1) * 64, wc = (wave & 1) * 64;
  int quad = lane >> 4, l16 = lane & 15;

  const floatx4 z4 = {0.f, 0.f, 0.f, 0.f};
  floatx4 acc[4][4];
#pragma unroll
  for (int i = 0; i < 4; ++i)
#pragma unroll
    for (int j = 0; j < 4; ++j) acc[i][j] = z4;

  for (int dy = 0; dy < 3; ++dy) {
    // padded input row hp = h + dy (covers src rows h-1..h+1), px 0 = wp w0
    const char* abase = (const char*)(gi + (((size_t)b * HP + (h + dy)) * WP + w0) * 256);
    for (int ck = 0; ck < 8; ++ck) {
      const char* asrc = abase + ck * 64;    // ck*32 ch * 2B
      __syncthreads();                       // previous interval fully consumed
      {  // stage A: 520 x 16B slots, swizzled source
        int s = tid, px = s >> 2, q = ((s & 3) - px) & 3;
        gl_lds16(asrc + px * 512 + q * 16, (char*)As + s * 16);
        s = tid + 256; px = s >> 2; q = ((s & 3) - px) & 3;
        gl_lds16(asrc + px * 512 + q * 16, (char*)As + s * 16);
        if (tid < 8) {
          s = tid + 512; px = s >> 2; q = ((s & 3) - px) & 3;
          gl_lds16(asrc + px * 512 + q * 16, (char*)As + s * 16);
        }
      }
#pragma unroll
      for (int r = 0; r < 6; ++r) {          // stage B: 3 dx tiles, 1536 slots
        int s = tid + r * 256;
        int dxt = s >> 9, si = s & 511;
        int n = si >> 2, q = ((si & 3) - n) & 3;
        int t = dy * 3 + dxt;
        gl_lds16((const char*)w1r + (((size_t)(t * 8 + ck)) * 4096 + n * 32 + q * 8) * 2,
                 (char*)Bs + s * 16);
      }
      __syncthreads();
#pragma unroll
      for (int dx = 0; dx < 3; ++dx) {
        bf16x8 af[4], bfr[4];
#pragma unroll
        for (int mi = 0; mi < 4; ++mi) {
          int px = wr + mi * 16 + l16 + dx;  // tile px = out m + dx
          af[mi] = *(const bf16x8*)((const char*)As + px * 64 + ((quad + px) & 3) * 16);
        }
#pragma unroll
        for (int ni = 0; ni < 4; ++ni) {
          int n = wc + ni * 16 + l16;
          bfr[ni] = *(const bf16x8*)((const char*)Bs + dx * 8192 + n * 64 + ((quad + n) & 3) * 16);
        }
#pragma unroll
        for (int mi = 0; mi < 4; ++mi)
#pragma unroll
          for (int ni = 0; ni < 4; ++ni)
            acc[mi][ni] = __builtin_amdgcn_mfma_f32_16x16x32_bf16(
                af[mi], bfr[ni], acc[mi][ni], 0, 0, 0);
      }
    }
  }
  size_t hrow = (((size_t)b * HP + (h + 1)) * WP + (w0 + 1)) * 128;
#pragma unroll
  for (int ni = 0; ni < 4; ++ni) {
    int n = wc + ni * 16 + l16;
    float sc = bnss[n], sh = bnss[128 + n];
#pragma unroll
    for (int mi = 0; mi < 4; ++mi)
#pragma unroll
      for (int r = 0; r < 4; ++r) {
        int m = wr + mi * 16 + quad * 4 + r;
        float v = fmaf(acc[mi][ni][r], sc, sh);
        hb[hrow + (size_t)m * 128 + n] = f2bf(fmaxf(v, 0.f));
      }
  }
}

// ---------- conv2: 3x3 128->9 (N padded to 16) + bias + sigmoid ----------
// Same restructure: dy outer, 258-px full-row A tile, 3 dx B tiles,
// 12 MFMA/wave per interval, 12 intervals.
__global__ __launch_bounds__(256) void k_conv2(
    const unsigned short* __restrict__ hb,   // [B][HP][WP][128] bf16
    const unsigned short* __restrict__ w2r,  // [9][4][16][32]   bf16
    const float* __restrict__ bg2,
    float* __restrict__ gates) {
  __shared__ __align__(16) unsigned short As[1032 * 8];  // 258 px x 32 ch = 16512 B
  __shared__ __align__(16) unsigned short Bs[192 * 8];   // 3 x (16 x 32) = 3072 B
  int tid = threadIdx.x;
  int blk = blockIdx.x;                      // b*256 + h
  int h = blk & 255, b = blk >> 8;
  int wave = tid >> 6, lane = tid & 63;
  int quad = lane >> 4, l16 = lane & 15;

  const floatx4 z4 = {0.f, 0.f, 0.f, 0.f};
  floatx4 acc[4];
#pragma unroll
  for (int i = 0; i < 4; ++i) acc[i] = z4;

  for (int dy = 0; dy < 3; ++dy) {
    const char* abase = (const char*)(hb + ((size_t)b * HP + (h + dy)) * WP * 128);
    for (int ck = 0; ck < 4; ++ck) {
      const char* asrc = abase + ck * 64;
      __syncthreads();
#pragma unroll
      for (int r = 0; r < 4; ++r) {          // stage A: 1032 slots
        int s = tid + r * 256;
        int px = s >> 2, q = ((s & 3) - px) & 3;
        gl_lds16(asrc + px * 256 + q * 16, (char*)As + s * 16);
      }
      if (tid < 8) {
        int s = 1024 + tid;
        int px = s >> 2, q = ((s & 3) - px) & 3;
        gl_lds16(asrc + px * 256 + q * 16, (char*)As + s * 16);
      }
      if (tid < 192) {                       // stage B: 3 tiles x 64 slots
        int s = tid;
        int dxt = s >> 6, si = s & 63;
        int n = si >> 2, q = ((si & 3) - n) & 3;
        int t = dy * 3 + dxt;
        gl_lds16((const char*)w2r + (((size_t)(t * 4 + ck)) * 512 + n * 32 + q * 8) * 2,
                 (char*)Bs + s * 16);
      }
      __syncthreads();
#pragma unroll
      for (int dx = 0; dx < 3; ++dx) {
        int n = l16;
        bf16x8 bfr = *(const bf16x8*)((const char*)Bs + dx * 1024 + n * 64 + ((quad + n) & 3) * 16);
#pragma unroll
        for (int mi = 0; mi < 4; ++mi) {
          int px = wave * 64 + mi * 16 + l16 + dx;
          bf16x8 af = *(const bf16x8*)((const char*)As + px * 64 + ((quad + px) & 3) * 16);
          acc[mi] = __builtin_amdgcn_mfma_f32_16x16x32_bf16(af, bfr, acc[mi], 0, 0, 0);
        }
      }
    }
  }
  if (l16 < 9) {
    float bias = bg2[l16];
    size_t gbase = ((size_t)b * 9 + l16) * PIX + h * 256;
#pragma unroll
    for (int mi = 0; mi < 4; ++mi)
#pragma unroll
      for (int r = 0; r < 4; ++r) {
        int m = wave * 64 + mi * 16 + quad * 4 + r;
        float v = acc[mi][r] + bias;
        gates[gbase + m] = 1.f / (1.f + __expf(-v));
      }
  }
}

// ---------- propagation iteration ----------
__global__ __launch_bounds__(256) void k_prop(
    const float* __restrict__ gates, const float* __restrict__ rin,
    float* __restrict__ rout, int final_) {
  int i = blockIdx.x * 256 + threadIdx.x;    // b*PIX + p
  int b = i >> 16, p = i & 65535;
  int h = p >> 8, w = p & 255;
  const float* g = gates + (size_t)b * 9 * PIX + p;
  const float* r = rin + (size_t)b * PIX;
  const int DY[9] = {-1, -1, 0, 1, 1, 1, 0, -1, 0};
  const int DX[9] = {0, 1, 1, 1, 0, -1, -1, -1, 0};
  float deg = 0.f, agg = 0.f;
#pragma unroll
  for (int d = 0; d < 9; ++d) {
    float gd = g[(size_t)d * PIX];
    deg += gd;
    int hh = h - DY[d], ww = w - DX[d];
    float rv = (hh >= 0 && hh < 256 && ww >= 0 && ww < 256) ? r[hh * 256 + ww] : 0.f;
    agg = fmaf(gd, rv, agg);
  }
  float rv = 0.3f * r[p] + 0.7f * agg / (deg + 1e-6f);
  if (final_) rv = fminf(fmaxf(rv, 0.f), 1.f);
  rout[i] = rv;
}

extern "C" void kernel_launch(void* const* d_in, const int* in_sizes, int n_in,
                              void* d_out, int out_size, void* d_ws, size_t ws_size,
                              hipStream_t stream) {
  const float* x     = (const float*)d_in[0];
  const float* y     = (const float*)d_in[1];
  const float* Wx    = (const float*)d_in[2];
  const float* Wy    = (const float*)d_in[3];
  const float* Wg1   = (const float*)d_in[4];
  const float* gamma = (const float*)d_in[5];
  const float* beta  = (const float*)d_in[6];
  const float* mean  = (const float*)d_in[7];
  const float* var   = (const float*)d_in[8];
  const float* Wg2   = (const float*)d_in[9];
  const float* bg2   = (const float*)d_in[10];

  char* ws = (char*)d_ws;
  size_t o = 0;
  auto alloc = [&](size_t sz) { char* p = ws + o; o += (sz + 255) & ~(size_t)255; return p; };
  unsigned short* gi    = (unsigned short*)alloc((size_t)B_ * HP * WP * 256 * 2);  // 272.6 MB
  unsigned short* hb    = (unsigned short*)alloc((size_t)B_ * HP * WP * 128 * 2);  // 136.3 MB
  float*          gates = (float*)alloc((size_t)B_ * 9 * PIX * 4);                 // 18.9 MB
  float*          r0    = (float*)alloc((size_t)B_ * PIX * 4);
  float*          r1    = (float*)alloc((size_t)B_ * PIX * 4);
  unsigned short* w1r   = (unsigned short*)alloc(294912 * 2);
  unsigned short* w2r   = (unsigned short*)alloc(18432 * 2);
  unsigned short* wemb  = (unsigned short*)alloc(8192 * 2);
  float*          bnss  = (float*)alloc(256 * 4);

  hipLaunchKernelGGL(k_prep_w1, dim3(1152), dim3(256), 0, stream, Wg1, w1r);
  hipLaunchKernelGGL(k_prep_w2, dim3(72), dim3(256), 0, stream, Wg2, w2r);
  hipLaunchKernelGGL(k_prep_wemb, dim3(32), dim3(256), 0, stream, Wx, Wy, wemb);
  hipLaunchKernelGGL(k_prep_bn, dim3(1), dim3(256), 0, stream,
                     gamma, beta, mean, var, bnss);
  hipLaunchKernelGGL(k_zero_border, dim3((8 * 1028 * 192 + 255) / 256), dim3(256), 0, stream,
                     (unsigned int*)gi, (unsigned int*)hb);
  hipLaunchKernelGGL(k_embed, dim3(4096), dim3(256), 0, stream,
                     x, y, wemb, (unsigned int*)gi, r0);
  hipLaunchKernelGGL(k_conv1, dim3(4096), dim3(256), 0, stream, gi, w1r, bnss, hb);
  hipLaunchKernelGGL(k_conv2, dim3(2048), dim3(256), 0, stream, hb, w2r, bg2, gates);
  hipLaunchKernelGGL(k_prop, dim3(2048), dim3(256), 0, stream, gates, r0, r1, 0);
  hipLaunchKernelGGL(k_prop, dim3(2048), dim3(256), 0, stream, gates, r1, (float*)d_out, 1);
}